// Round 5
// baseline (158.857 us; speedup 1.0000x reference)
//
#include <hip/hip_runtime.h>
#include <hip/hip_bf16.h>
#include <stdint.h>

typedef __bf16 bf16_t;
typedef bf16_t bf16x8 __attribute__((ext_vector_type(8)));
typedef float f32x4 __attribute__((ext_vector_type(4)));

#define BM 256
#define BN 256
#define BK 64

// ---------------------------------------------------------------------------
// async global->LDS 16B copy. LDS dest is wave-uniform base; HW adds lane*16.
// Global source IS per-lane -> swizzled LDS content via pre-swizzled source.
// ---------------------------------------------------------------------------
__device__ __forceinline__ void gload_lds16(const void* g, void* l) {
  __builtin_amdgcn_global_load_lds(
      (const __attribute__((address_space(1))) uint32_t*)g,
      (__attribute__((address_space(3))) uint32_t*)l, 16, 0, 0);
}

// ---------------------------------------------------------------------------
// fused fp32->bf16 conversion: blocks [0,gx) convert x, [gx,..) convert
// weight (per-out-channel scale folded in). 8 elems/thread, grid-stride.
// ---------------------------------------------------------------------------
__global__ __launch_bounds__(256) void cvt_kernel(
    const float* __restrict__ x, bf16_t* __restrict__ xo, int n8x,
    const float* __restrict__ w, const float* __restrict__ scale,
    bf16_t* __restrict__ wo, int k8, int n8w, int gx) {
  if ((int)blockIdx.x < gx) {
    int stride = gx * blockDim.x;
    for (int i = blockIdx.x * blockDim.x + threadIdx.x; i < n8x; i += stride) {
      const f32x4* p = (const f32x4*)x + 2 * (size_t)i;
      f32x4 a = p[0], b = p[1];
      bf16x8 o;
#pragma unroll
      for (int r = 0; r < 4; ++r) { o[r] = (bf16_t)a[r]; o[r + 4] = (bf16_t)b[r]; }
      *((bf16x8*)xo + i) = o;
    }
  } else {
    int stride = (gridDim.x - gx) * blockDim.x;
    for (int i = (blockIdx.x - gx) * blockDim.x + threadIdx.x; i < n8w;
         i += stride) {
      int row = i / k8;
      float s = scale[row];
      const f32x4* p = (const f32x4*)w + 2 * (size_t)i;
      f32x4 a = p[0], b = p[1];
      bf16x8 o;
#pragma unroll
      for (int r = 0; r < 4; ++r) {
        o[r] = (bf16_t)(a[r] * s);
        o[r + 4] = (bf16_t)(b[r] * s);
      }
      *((bf16x8*)wo + i) = o;
    }
  }
}

// ---------------------------------------------------------------------------
// 256x256 bf16 GEMM, both K-major (B^T). 8 waves (2Mx4N), per-wave out
// 128x64. m201-faithful 4-phase/K-tile schedule, each phase:
//   { ds_read this phase's frags | stage 1 unit | BAR | lgkmcnt(0) |
//     setprio(1) 16xMFMA setprio(0) | [vmcnt(4) @P4 only] | BAR }
// Counted vmcnt NEVER 0 in steady state: ring keeps up to 12 staged loads
// in flight. Units: 16KB = 256 rows x 32K (K-half) of A or B.
//   buf bb=t&1: A-K0 @bb+0, A-K1 @bb+16K, B-K0 @bb+32K, B-K1 @bb+48K.
// Stage schedule (tile t): P1: A-K1(t+1)->nb  P2: B-K1(t+1)->nb
//                          P3: A-K0(t+2)->bb  P4: B-K0(t+2)->bb
// vmcnt(4)@P4(t) drains P1/P2(t) stages (needed by P3(t+1)) and everything
// older (P3/P4(t-1) stages needed by P1(t+1)).
//
// LDS swizzle: chunk-XOR s(row)=(row>>1)&3 at 16B granularity — verified
// 0 SQ_LDS_BANK_CONFLICT; staging pre-applies it on the global source.
// ---------------------------------------------------------------------------
__global__ __launch_bounds__(512, 2) void gemm256(
    const bf16_t* __restrict__ A, const bf16_t* __restrict__ B,
    const float* __restrict__ bias, float* __restrict__ C,
    int M, int N, int K) {
  __shared__ __attribute__((aligned(16))) char lds[131072];

  const int tid = threadIdx.x;
  const int lane = tid & 63;
  const int wave = tid >> 6;
  const int wm = wave >> 2;   // 0..1  (row half of tile)
  const int wn = wave & 3;    // 0..3  (col quarter of tile)

  // XCD-aware bijective swizzle
  int nwg = gridDim.x;
  int wg = blockIdx.x;
  if ((nwg & 7) == 0) { int cpx = nwg >> 3; wg = (wg & 7) * cpx + (wg >> 3); }
  const int ntn = N / BN;
  const int tm = wg / ntn;
  const int tn = wg % ntn;

  const size_t Kb = (size_t)K * 2;
  const char* gApan = (const char*)A + (size_t)tm * BM * Kb;
  const char* gBpan = (const char*)B + (size_t)tn * BN * Kb;

  // ---- per-lane read bases (row*64 + swizzled 16B chunk), const offsets ----
  // row bases are multiples of 16 -> swizzle term (row>>1)&3 == (lane>>1)&3.
  const int xc = (((lane >> 4) ^ ((lane >> 1) & 3)) << 4);
  const int aBase = (wm * 128 + (lane & 15)) * 64 + xc;  // + ch*4096 + i*1024
  const int bBase = (wn * 64 + (lane & 15)) * 64 + xc;   // + j*1024

  // ---- staging offsets: wave w covers rows [(2w+s)*16, +16) of a unit ----
  size_t srcoff[2];
  int ldst[2];
#pragma unroll
  for (int s = 0; s < 2; ++s) {
    int r = (wave * 2 + s) * 16 + (lane >> 2);
    int c = (lane & 3) ^ ((lane >> 3) & 3);
    srcoff[s] = (size_t)r * Kb + (size_t)(c << 4);
    ldst[s] = (wave * 2 + s) * 1024;
  }

#define STAGE_U(dstbase, pan, kbyte)                                          \
  {                                                                           \
    gload_lds16((pan) + srcoff[0] + (size_t)(kbyte), lds + (dstbase) + ldst[0]); \
    gload_lds16((pan) + srcoff[1] + (size_t)(kbyte), lds + (dstbase) + ldst[1]); \
  }
#define RD_A(dst, unitbase, ch)                                               \
  _Pragma("unroll") for (int i_ = 0; i_ < 4; ++i_)                            \
      dst[i_] = *(const bf16x8*)(lds + (unitbase) + aBase + (ch) * 4096 +     \
                                 i_ * 1024);
#define RD_B(dst, unitbase)                                                   \
  _Pragma("unroll") for (int j_ = 0; j_ < 4; ++j_)                            \
      dst[j_] = *(const bf16x8*)(lds + (unitbase) + bBase + j_ * 1024);
#define MFMA16(ab, bb_, accbase)                                              \
  __builtin_amdgcn_s_setprio(1);                                              \
  _Pragma("unroll") for (int i_ = 0; i_ < 4; ++i_)                            \
      _Pragma("unroll") for (int j_ = 0; j_ < 4; ++j_)                        \
          acc[(accbase) + i_][j_] = __builtin_amdgcn_mfma_f32_16x16x32_bf16(  \
              ab[i_], bb_[j_], acc[(accbase) + i_][j_], 0, 0, 0);             \
  __builtin_amdgcn_s_setprio(0);
#define WAIT_LGKM0() asm volatile("s_waitcnt lgkmcnt(0)" ::: "memory")
#define WAIT_VM(n)   asm volatile("s_waitcnt vmcnt(" #n ")" ::: "memory")
#define BAR()        __builtin_amdgcn_s_barrier()

  f32x4 acc[8][4];
#pragma unroll
  for (int a = 0; a < 8; ++a)
#pragma unroll
    for (int j = 0; j < 4; ++j) acc[a][j] = (f32x4)0.0f;

  const int NT = K / BK;

  // ---- prologue: tile0 (4 units) + tile1 K0 (2 units); 2 left in flight ----
  STAGE_U(0,             gApan, 0);
  STAGE_U(32768,         gBpan, 0);
  STAGE_U(16384,         gApan, 64);
  STAGE_U(49152,         gBpan, 64);
  if (NT > 1) {
    STAGE_U(65536,         gApan, 128);
    STAGE_U(65536 + 32768, gBpan, 128);
    WAIT_VM(4);
  } else {
    WAIT_VM(0);
  }
  BAR();

  bf16x8 af[4], bf[4];

  for (int t = 0; t < NT; ++t) {
    const int bb = (t & 1) << 16;
    const int nb = bb ^ 65536;
    const size_t kb1 = (size_t)(t + 1) * 128;
    const size_t kb2 = (size_t)(t + 2) * 128;
    const bool st1 = (t + 1) < NT;
    const bool st2 = (t + 2) < NT;

    // ---- P1: A(ch0,K0) x B(K0) -> acc[0..3] ----
    RD_A(af, bb, 0);
    RD_B(bf, bb + 32768);
    if (st1) STAGE_U(nb + 16384, gApan, kb1 + 64);   // A-K1(t+1)
    BAR();
    WAIT_LGKM0();
    MFMA16(af, bf, 0);
    BAR();

    // ---- P2: A(ch1,K0) x B(K0) -> acc[4..7] ----
    RD_A(af, bb, 1);
    if (st1) STAGE_U(nb + 49152, gBpan, kb1 + 64);   // B-K1(t+1)
    BAR();
    WAIT_LGKM0();
    MFMA16(af, bf, 4);
    BAR();

    // ---- P3: A(ch0,K1) x B(K1) -> acc[0..3] ----
    RD_A(af, bb + 16384, 0);
    RD_B(bf, bb + 49152);
    if (st2) STAGE_U(bb, gApan, kb2);                // A-K0(t+2)
    BAR();
    WAIT_LGKM0();
    MFMA16(af, bf, 0);
    BAR();

    // ---- P4: A(ch1,K1) x B(K1) -> acc[4..7] ----
    RD_A(af, bb + 16384, 1);
    if (st2) STAGE_U(bb + 32768, gBpan, kb2);        // B-K0(t+2)
    BAR();
    WAIT_LGKM0();
    MFMA16(af, bf, 4);
    if (st2) { WAIT_VM(4); } else { WAIT_VM(0); }
    BAR();
  }
#undef STAGE_U
#undef RD_A
#undef RD_B
#undef MFMA16
#undef WAIT_LGKM0
#undef WAIT_VM
#undef BAR

  // ---- epilogue: bias + store. C/D: col=lane&15, row=(lane>>4)*4+r ----
  const int row0 = tm * BM + wm * 128;
  const int col0 = tn * BN + wn * 64;
#pragma unroll
  for (int j = 0; j < 4; ++j) {
    int c = col0 + j * 16 + (lane & 15);
    float bv = bias[c];
#pragma unroll
    for (int a = 0; a < 8; ++a) {
      int ch = a >> 2, i = a & 3;
      int rbase = row0 + ch * 64 + i * 16 + ((lane >> 4) << 2);
#pragma unroll
      for (int r = 0; r < 4; ++r)
        C[(size_t)(rbase + r) * N + c] = acc[a][j][r] + bv;
    }
  }
}

// ---------------------------------------------------------------------------
// fallback: naive fp32 (only if workspace/shape unsuitable — correctness net)
// ---------------------------------------------------------------------------
__global__ void fallback_gemm(const float* __restrict__ x,
                              const float* __restrict__ w,
                              const float* __restrict__ s,
                              const float* __restrict__ b,
                              float* __restrict__ out, int M, int N, int K) {
  int o = blockIdx.x * blockDim.x + threadIdx.x;
  if (o >= M * N) return;
  int m = o / N, n = o % N;
  const float* xr = x + (size_t)m * K;
  const float* wr = w + (size_t)n * K;
  float acc = 0.f;
  for (int k = 0; k < K; ++k) acc += xr[k] * wr[k];
  out[o] = acc * s[n] + b[n];
}

extern "C" void kernel_launch(void* const* d_in, const int* in_sizes, int n_in,
                              void* d_out, int out_size, void* d_ws,
                              size_t ws_size, hipStream_t stream) {
  const float* x = (const float*)d_in[0];
  const float* w = (const float*)d_in[1];
  const float* sc = (const float*)d_in[2];
  const float* bias = (const float*)d_in[3];
  float* out = (float*)d_out;

  const int N = in_sizes[2];        // out_features (weight_scale length)
  const int K = in_sizes[1] / N;    // in_features
  const int M = in_sizes[0] / K;    // tokens

  const size_t need = ((size_t)M * K + (size_t)N * K) * sizeof(bf16_t);
  const bool fast = (ws_size >= need) && (M % BM == 0) && (N % BN == 0) &&
                    (K % BK == 0) && (K / BK >= 1);

  if (fast) {
    bf16_t* xb = (bf16_t*)d_ws;
    bf16_t* wb = xb + (size_t)M * K;

    int n8x = (M * K) / 8;
    int n8w = (N * K) / 8;
    const int gx = 2048;
    cvt_kernel<<<gx + 2048, 256, 0, stream>>>(x, xb, n8x, w, sc, wb, K / 8,
                                              n8w, gx);

    dim3 grid((M / BM) * (N / BN));
    gemm256<<<grid, 512, 0, stream>>>(xb, wb, bias, out, M, N, K);
  } else {
    int total = M * N;
    fallback_gemm<<<(total + 255) / 256, 256, 0, stream>>>(x, w, sc, bias, out,
                                                           M, N, K);
  }
}